// Round 17
// baseline (219.982 us; speedup 1.0000x reference)
//
#include <hip/hip_runtime.h>
#include <stdint.h>

#define B_    4
#define C_    256
#define W_    4096
#define DQK_  32
#define NT64_ 64      // 64-wide n tiles per batch
#define TSZ_  16384   // shorts per x0f tile (8 wb x 4 frag x 64 lane x 8)

typedef short bf16x8 __attribute__((ext_vector_type(8)));
typedef float f32x4  __attribute__((ext_vector_type(4)));

__device__ __forceinline__ float fexp2f(float x){
#if __has_builtin(__builtin_amdgcn_exp2f)
  return __builtin_amdgcn_exp2f(x);
#else
  return exp2f(x);
#endif
}
__device__ __forceinline__ float frcpf(float x){
#if __has_builtin(__builtin_amdgcn_rcpf)
  return __builtin_amdgcn_rcpf(x);
#else
  return 1.0f / x;
#endif
}
// single-instruction packed f32->bf16 (RTNE)
__device__ __forceinline__ uint32_t cvtpk(float a, float b){
  uint32_t r;
  asm("v_cvt_pk_bf16_f32 %0, %1, %2" : "=v"(r) : "v"(a), "v"(b));
  return r;
}
__device__ __forceinline__ unsigned short bf16c(float f){
  return (unsigned short)cvtpk(f, f);
}

// ---------------------------------------------------------------------------
// K1: UNCHANGED from R15 (wave-uniform weight c-slices -> scalar broadcasts).
// ---------------------------------------------------------------------------
__global__ __launch_bounds__(512) void sa_prep(
    const float* __restrict__ x0, const float* __restrict__ x1,
    const float* __restrict__ wq, const float* __restrict__ bq,
    const float* __restrict__ wk, const float* __restrict__ bk,
    unsigned short* __restrict__ qf, unsigned short* __restrict__ kT,
    unsigned short* __restrict__ x0f)
{
  const int b    = blockIdx.y;
  const int nt   = blockIdx.x;                 // 64-n tile index
  const int tid  = threadIdx.x;
  const int lane = tid & 63;
  const int cq   = __builtin_amdgcn_readfirstlane(tid >> 6);   // 0..7, uniform
  const int n    = nt * 64 + lane;
  const int lr   = lane & 15, lg = lane >> 4;
  const size_t bw = (size_t)b * ((size_t)C_ * W_) + n;

  __shared__ union {
    unsigned short xs[256 * 68];   // bf16 stage [c][n-local], pitch 68
    float red[8][64][33];          // cross-wave reduce
  } sm;

  float accq[DQK_], acck[DQK_];
  #pragma unroll
  for (int d = 0; d < DQK_; ++d){ accq[d] = 0.f; acck[d] = 0.f; }

  const int c0 = cq * 32;
  for (int i = 0; i < 32; ++i){
    const int c = c0 + i;                      // wave-uniform
    const size_t off = bw + (size_t)c * W_;
    const float v0 = x0[off];
    const float v1 = x1[off];
    sm.xs[c * 68 + lane] = bf16c(v0);
    #pragma unroll
    for (int d = 0; d < DQK_; ++d){
      accq[d] = fmaf(wq[d * C_ + c], v0, accq[d]);   // scalar loads (uniform)
      acck[d] = fmaf(wk[d * C_ + c], v1, acck[d]);
    }
  }

  // ---- flush x0f (intra-wave dependency only) ----
  {
    unsigned short* xt = x0f + (size_t)(b * NT64_ + nt) * TSZ_;
    #pragma unroll
    for (int ct = 0; ct < 2; ++ct)
      #pragma unroll
      for (int ks = 0; ks < 2; ++ks){
        uint4 v = *(const uint4*)&sm.xs[(c0 + ct * 16 + lr) * 68 + ks * 32 + lg * 8];
        *(uint4*)(xt + ((size_t)((cq * 2 + ct) * 2 + ks) * 64 + lane) * 8) = v;
      }
  }
  __syncthreads();   // xs reads done -> red may overwrite

  // ---- q reduce + fragment-layout pack ----
  #pragma unroll
  for (int d = 0; d < DQK_; ++d) sm.red[cq][lane][d] = accq[d];
  __syncthreads();
  {
    const int nl = tid & 63, dg = tid >> 6;
    const int d0 = dg * 4;
    float s[4];
    #pragma unroll
    for (int j = 0; j < 4; ++j){
      float t = bq[d0 + j];
      #pragma unroll
      for (int g = 0; g < 8; ++g) t += sm.red[g][nl][d0 + j];
      s[j] = t;
    }
    uint2 pk; pk.x = cvtpk(s[0], s[1]); pk.y = cvtpk(s[2], s[3]);
    const int ng = nt * 64 + nl;
    const size_t addr = (((size_t)b * 256 + (ng >> 4)) * 64
                         + (ng & 15) + ((dg >> 1) << 4)) * 8 + (dg & 1) * 4;
    *(uint2*)(qf + addr) = pk;
  }
  __syncthreads();

  // ---- k reduce + row-major pack (scaled) ----
  #pragma unroll
  for (int d = 0; d < DQK_; ++d) sm.red[cq][lane][d] = acck[d];
  __syncthreads();
  {
    const float SCL = 0.0625f * 1.44269504088896340736f; // 1/sqrt(256)*log2(e)
    const int nl = tid & 63, dg = tid >> 6;
    const int d0 = dg * 4;
    float s[4];
    #pragma unroll
    for (int j = 0; j < 4; ++j){
      float t = bk[d0 + j];
      #pragma unroll
      for (int g = 0; g < 8; ++g) t += sm.red[g][nl][d0 + j];
      s[j] = t * SCL;
    }
    uint2 pk; pk.x = cvtpk(s[0], s[1]); pk.y = cvtpk(s[2], s[3]);
    *(uint2*)(kT + ((size_t)b * W_ + nt * 64 + nl) * DQK_ + d0) = pk;
  }
}

// ---------------------------------------------------------------------------
// K2 (R17): PHASE DECORRELATION. m-tile 16, 4 waves (256 thr), grid 1024 ->
// 4 independent barrier groups per CU. One block's PV (LDS+MFMA) overlaps
// another's load burst and a third's store drain -> phase-sum becomes
// phase-max. Mechanical shrink of R15: wave = nq (0..3), acc c64/wave,
// P tile 16x64 (2x2KB dbuf), same swizzles. af loads just-in-time in 2
// groups of 4 (VGPR <= 128 for 4 blocks/CU).
// ---------------------------------------------------------------------------
__global__ __launch_bounds__(256, 4) void sa_fused(
    const unsigned short* __restrict__ qf, const unsigned short* __restrict__ kT,
    const unsigned short* __restrict__ x0f, const float* __restrict__ x1,
    const float* __restrict__ gamma,
    float* __restrict__ out, float* __restrict__ att)
{
  const int lb = blockIdx.x;
  const int b    = (lb & 7) >> 1;                    // batch -> XCD pair
  const int mblk = ((lb >> 3) << 1) | (lb & 1);      // 0..255
  const int m0 = mblk * 16;
  const int tid = threadIdx.x;
  const int lane = tid & 63;
  const int wid = tid >> 6;                          // 0..3
  const int lr = lane & 15, lg = lane >> 4;
  const int nq = wid;                                // n-quarter 0..3

  __shared__ __align__(16) unsigned short Plds[2][16 * 64]; // 2 x 2KB, swizzled
  __shared__ float ssum[4][16];

  const bf16x8 kf = *(const bf16x8*)(kT + ((size_t)b * W_ + m0 + lr) * DQK_ + lg * 8);
  const unsigned short* qfw = qf + ((size_t)b * 256 * 64 + (size_t)nq * 64 + lane) * 8;
  const unsigned short* afw = x0f + (size_t)b * NT64_ * TSZ_ + wid * 4096 + lane * 8;

  // ---- pass 1: denominators (energy-only), q prefetched 1 iter ahead ----
  float ps = 0.f;
  {
    const unsigned short* qp = qfw + 2048;
    bf16x8 qv = *(const bf16x8*)qfw;
    for (int s = 0; s < NT64_; ++s){
      bf16x8 qn = *(const bf16x8*)qp;
      qp = (s == NT64_ - 2) ? qfw : (qp + 2048);
      f32x4 e = __builtin_amdgcn_mfma_f32_16x16x32_bf16(qv, kf, (f32x4){0.f,0.f,0.f,0.f}, 0, 0, 0);
      ps += (fexp2f(e[0]) + fexp2f(e[1])) + (fexp2f(e[2]) + fexp2f(e[3]));
      qv = qn;
    }
  }
  ps += __shfl_xor(ps, 16);
  ps += __shfl_xor(ps, 32);
  if (lane < 16) ssum[nq][lane] = ps;
  __syncthreads();
  const float is = frcpf(ssum[0][lr] + ssum[1][lr] + ssum[2][lr] + ssum[3][lr]);

  // ---- pass 2 ----
  f32x4 acc[4];
  #pragma unroll
  for (int ct = 0; ct < 4; ++ct) acc[ct] = (f32x4){0.f,0.f,0.f,0.f};

  const int pw = lr * 64 + (((nq * 2 + (lg >> 1)) ^ (lr & 7)) << 3) + (lg & 1) * 4;
  const int pfo0 = lr * 64 + (((0 * 4 + lg) ^ (lr & 7)) << 3);
  const int pfo1 = lr * 64 + (((1 * 4 + lg) ^ (lr & 7)) << 3);

  const unsigned short* qp = qfw + 2048;     // q tile for s+1
  const unsigned short* afp = afw;           // x0f tile for s (in-iter use)
  float* attw = att + ((size_t)b * W_ + m0 + lr) * W_ + nq * 16 + lg * 4;

  bf16x8 qv = *(const bf16x8*)qfw;           // q for s=0
  for (int s = 0; s < NT64_; ++s){
    const int cur = s & 1;

    // energy quarter -> P[cur]
    f32x4 e = __builtin_amdgcn_mfma_f32_16x16x32_bf16(qv, kf, (f32x4){0.f,0.f,0.f,0.f}, 0, 0, 0);
    f32x4 p;
    #pragma unroll
    for (int r = 0; r < 4; ++r) p[r] = fexp2f(e[r]) * is;
    uint2 pv; pv.x = cvtpk(p[0], p[1]); pv.y = cvtpk(p[2], p[3]);
    *(uint2*)(&Plds[cur][0] + pw) = pv;

    // pure-LDS barrier: P[cur] visible; NO vmcnt drain
    asm volatile("s_waitcnt lgkmcnt(0)" ::: "memory");
    __builtin_amdgcn_sched_barrier(0);
    __builtin_amdgcn_s_barrier();

    // prefetch next q + store att(s)
    qv = *(const bf16x8*)qp;
    qp = (s == NT64_ - 2) ? qfw : (qp + 2048);
    __builtin_nontemporal_store(p, (f32x4*)attw);
    attw += 64;

    // PV: A = x0 fragments (just-in-time regs, 2 groups), B = P[cur]
    const unsigned short* Pb = &Plds[cur][0];
    bf16x8 pf0 = *(const bf16x8*)(Pb + pfo0);
    bf16x8 pf1 = *(const bf16x8*)(Pb + pfo1);
    __builtin_amdgcn_s_setprio(1);
    {
      bf16x8 a0 = *(const bf16x8*)(afp);
      bf16x8 a1 = *(const bf16x8*)(afp + 512);
      bf16x8 a2 = *(const bf16x8*)(afp + 1024);
      bf16x8 a3 = *(const bf16x8*)(afp + 1536);
      acc[0] = __builtin_amdgcn_mfma_f32_16x16x32_bf16(a0, pf0, acc[0], 0, 0, 0);
      acc[0] = __builtin_amdgcn_mfma_f32_16x16x32_bf16(a1, pf1, acc[0], 0, 0, 0);
      acc[1] = __builtin_amdgcn_mfma_f32_16x16x32_bf16(a2, pf0, acc[1], 0, 0, 0);
      acc[1] = __builtin_amdgcn_mfma_f32_16x16x32_bf16(a3, pf1, acc[1], 0, 0, 0);
    }
    {
      bf16x8 a4 = *(const bf16x8*)(afp + 2048);
      bf16x8 a5 = *(const bf16x8*)(afp + 2560);
      bf16x8 a6 = *(const bf16x8*)(afp + 3072);
      bf16x8 a7 = *(const bf16x8*)(afp + 3584);
      acc[2] = __builtin_amdgcn_mfma_f32_16x16x32_bf16(a4, pf0, acc[2], 0, 0, 0);
      acc[2] = __builtin_amdgcn_mfma_f32_16x16x32_bf16(a5, pf1, acc[2], 0, 0, 0);
      acc[3] = __builtin_amdgcn_mfma_f32_16x16x32_bf16(a6, pf0, acc[3], 0, 0, 0);
      acc[3] = __builtin_amdgcn_mfma_f32_16x16x32_bf16(a7, pf1, acc[3], 0, 0, 0);
    }
    __builtin_amdgcn_s_setprio(0);
    afp += TSZ_;
  }

  // ---- epilogue: out[c][m] = gamma*acc + x1 (nontemporal both ways) ----
  const float g = gamma[0];
  const float* x1b = x1 + (size_t)b * C_ * W_;
  float* outb = out + (size_t)b * C_ * W_;
  #pragma unroll
  for (int ct = 0; ct < 4; ++ct)
    #pragma unroll
    for (int r = 0; r < 4; ++r){
      const int c = wid * 64 + ct * 16 + lg * 4 + r;
      const size_t idx = (size_t)c * W_ + m0 + lr;
      const float xv = __builtin_nontemporal_load(&x1b[idx]);
      __builtin_nontemporal_store(fmaf(g, acc[ct][r], xv), &outb[idx]);
    }
}

extern "C" void kernel_launch(void* const* d_in, const int* in_sizes, int n_in,
                              void* d_out, int out_size, void* d_ws, size_t ws_size,
                              hipStream_t stream)
{
  (void)in_sizes; (void)n_in; (void)out_size; (void)ws_size;
  const float* x0    = (const float*)d_in[0];
  const float* x1    = (const float*)d_in[1];
  const float* wq    = (const float*)d_in[2];
  const float* bq    = (const float*)d_in[3];
  const float* wk    = (const float*)d_in[4];
  const float* bk    = (const float*)d_in[5];
  const float* gamma = (const float*)d_in[6];

  unsigned short* qf  = (unsigned short*)d_ws;                   // 1 MB (fragment layout)
  unsigned short* kT  = qf + (size_t)B_ * W_ * DQK_;             // 1 MB
  unsigned short* x0f = kT + (size_t)B_ * W_ * DQK_;             // 8 MB fragment tiles

  float* out = (float*)d_out;                                    // [B][C][W]
  float* att = out + (size_t)B_ * C_ * W_;                       // [B][W][W]

  sa_prep <<<dim3(64, 4), 512, 0, stream>>>(x0, x1, wq, bq, wk, bk, qf, kT, x0f);
  sa_fused<<<1024, 256, 0, stream>>>(qf, kT, x0f, x1, gamma, out, att);
}

// Round 18
// 127.109 us; speedup vs baseline: 1.7307x; 1.7307x over previous
//
#include <hip/hip_runtime.h>
#include <stdint.h>

#define B_    4
#define C_    256
#define W_    4096
#define DQK_  32
#define NT64_ 64      // 64-wide n tiles per batch
#define TSZ_  16384   // shorts per x0f tile (8 wb x 4 frag x 64 lane x 8)

typedef short bf16x8 __attribute__((ext_vector_type(8)));
typedef float f32x4  __attribute__((ext_vector_type(4)));

__device__ __forceinline__ float fexp2f(float x){
#if __has_builtin(__builtin_amdgcn_exp2f)
  return __builtin_amdgcn_exp2f(x);
#else
  return exp2f(x);
#endif
}
__device__ __forceinline__ float frcpf(float x){
#if __has_builtin(__builtin_amdgcn_rcpf)
  return __builtin_amdgcn_rcpf(x);
#else
  return 1.0f / x;
#endif
}
// single-instruction packed f32->bf16 (RTNE)
__device__ __forceinline__ uint32_t cvtpk(float a, float b){
  uint32_t r;
  asm("v_cvt_pk_bf16_f32 %0, %1, %2" : "=v"(r) : "v"(a), "v"(b));
  return r;
}
__device__ __forceinline__ unsigned short bf16c(float f){
  return (unsigned short)cvtpk(f, f);
}

// ---------------------------------------------------------------------------
// K1: UNCHANGED from R15 (wave-uniform weight c-slices -> scalar broadcasts).
// ---------------------------------------------------------------------------
__global__ __launch_bounds__(512) void sa_prep(
    const float* __restrict__ x0, const float* __restrict__ x1,
    const float* __restrict__ wq, const float* __restrict__ bq,
    const float* __restrict__ wk, const float* __restrict__ bk,
    unsigned short* __restrict__ qf, unsigned short* __restrict__ kT,
    unsigned short* __restrict__ x0f)
{
  const int b    = blockIdx.y;
  const int nt   = blockIdx.x;                 // 64-n tile index
  const int tid  = threadIdx.x;
  const int lane = tid & 63;
  const int cq   = __builtin_amdgcn_readfirstlane(tid >> 6);   // 0..7, uniform
  const int n    = nt * 64 + lane;
  const int lr   = lane & 15, lg = lane >> 4;
  const size_t bw = (size_t)b * ((size_t)C_ * W_) + n;

  __shared__ union {
    unsigned short xs[256 * 68];   // bf16 stage [c][n-local], pitch 68
    float red[8][64][33];          // cross-wave reduce
  } sm;

  float accq[DQK_], acck[DQK_];
  #pragma unroll
  for (int d = 0; d < DQK_; ++d){ accq[d] = 0.f; acck[d] = 0.f; }

  const int c0 = cq * 32;
  for (int i = 0; i < 32; ++i){
    const int c = c0 + i;                      // wave-uniform
    const size_t off = bw + (size_t)c * W_;
    const float v0 = x0[off];
    const float v1 = x1[off];
    sm.xs[c * 68 + lane] = bf16c(v0);
    #pragma unroll
    for (int d = 0; d < DQK_; ++d){
      accq[d] = fmaf(wq[d * C_ + c], v0, accq[d]);   // scalar loads (uniform)
      acck[d] = fmaf(wk[d * C_ + c], v1, acck[d]);
    }
  }

  // ---- flush x0f (intra-wave dependency only) ----
  {
    unsigned short* xt = x0f + (size_t)(b * NT64_ + nt) * TSZ_;
    #pragma unroll
    for (int ct = 0; ct < 2; ++ct)
      #pragma unroll
      for (int ks = 0; ks < 2; ++ks){
        uint4 v = *(const uint4*)&sm.xs[(c0 + ct * 16 + lr) * 68 + ks * 32 + lg * 8];
        *(uint4*)(xt + ((size_t)((cq * 2 + ct) * 2 + ks) * 64 + lane) * 8) = v;
      }
  }
  __syncthreads();   // xs reads done -> red may overwrite

  // ---- q reduce + fragment-layout pack ----
  #pragma unroll
  for (int d = 0; d < DQK_; ++d) sm.red[cq][lane][d] = accq[d];
  __syncthreads();
  {
    const int nl = tid & 63, dg = tid >> 6;
    const int d0 = dg * 4;
    float s[4];
    #pragma unroll
    for (int j = 0; j < 4; ++j){
      float t = bq[d0 + j];
      #pragma unroll
      for (int g = 0; g < 8; ++g) t += sm.red[g][nl][d0 + j];
      s[j] = t;
    }
    uint2 pk; pk.x = cvtpk(s[0], s[1]); pk.y = cvtpk(s[2], s[3]);
    const int ng = nt * 64 + nl;
    const size_t addr = (((size_t)b * 256 + (ng >> 4)) * 64
                         + (ng & 15) + ((dg >> 1) << 4)) * 8 + (dg & 1) * 4;
    *(uint2*)(qf + addr) = pk;
  }
  __syncthreads();

  // ---- k reduce + row-major pack (scaled) ----
  #pragma unroll
  for (int d = 0; d < DQK_; ++d) sm.red[cq][lane][d] = acck[d];
  __syncthreads();
  {
    const float SCL = 0.0625f * 1.44269504088896340736f; // 1/sqrt(256)*log2(e)
    const int nl = tid & 63, dg = tid >> 6;
    const int d0 = dg * 4;
    float s[4];
    #pragma unroll
    for (int j = 0; j < 4; ++j){
      float t = bk[d0 + j];
      #pragma unroll
      for (int g = 0; g < 8; ++g) t += sm.red[g][nl][d0 + j];
      s[j] = t * SCL;
    }
    uint2 pk; pk.x = cvtpk(s[0], s[1]); pk.y = cvtpk(s[2], s[3]);
    *(uint2*)(kT + ((size_t)b * W_ + nt * 64 + nl) * DQK_ + d0) = pk;
  }
}

// ---------------------------------------------------------------------------
// K2: R16 structure (m-tile 64, 256 blocks, 8 waves = nq x mh), with ONE
// change: ALL stores/loads are NORMAL (through L2) — no nontemporal.
// Theory: NT stores bypass L2 and cap at ~11 GB/s/CU (limited non-cached
// write-combining buffers x ~1us HBM latency); normal stores retire into L2
// at line rate (fill kernels: 27 GB/s/CU). The NT cap sat under every other
// phase, explaining R6-R16's null results.
// ---------------------------------------------------------------------------
__global__ __launch_bounds__(512, 2) void sa_fused(
    const unsigned short* __restrict__ qf, const unsigned short* __restrict__ kT,
    const unsigned short* __restrict__ x0f, const float* __restrict__ x1,
    const float* __restrict__ gamma,
    float* __restrict__ out, float* __restrict__ att)
{
  const int lb = blockIdx.x;
  const int b    = (lb & 7) >> 1;                    // batch -> XCD pair
  const int mblk = ((lb >> 3) << 1) | (lb & 1);      // 0..63
  const int m0 = mblk * 64;
  const int tid = threadIdx.x;
  const int lane = tid & 63;
  const int wid = tid >> 6;                          // 0..7
  const int lr = lane & 15, lg = lane >> 4;
  const int nq = wid >> 1;                           // n-quarter 0..3
  const int mh = wid & 1;                            // m-half 0..1

  __shared__ __align__(16) unsigned short Plds[2][64 * 64]; // 2 x 8KB, swizzled
  __shared__ float ssum[4][64];

  const int row0 = mh * 32 + lr, row1 = row0 + 16;
  const bf16x8 kf0 = *(const bf16x8*)(kT + ((size_t)b * W_ + m0 + row0) * DQK_ + lg * 8);
  const bf16x8 kf1 = *(const bf16x8*)(kT + ((size_t)b * W_ + m0 + row1) * DQK_ + lg * 8);
  const unsigned short* qfw = qf + ((size_t)b * 256 * 64 + (size_t)nq * 64 + lane) * 8;
  const unsigned short* afw = x0f + (size_t)b * NT64_ * TSZ_ + wid * 2048 + lane * 8;

  // ---- pass 1: denominators (energy-only), q prefetched 1 iter ahead ----
  float ps0 = 0.f, ps1 = 0.f;
  {
    const unsigned short* qp = qfw + 2048;
    bf16x8 qv = *(const bf16x8*)qfw;
    for (int s = 0; s < NT64_; ++s){
      bf16x8 qn = *(const bf16x8*)qp;
      qp = (s == NT64_ - 2) ? qfw : (qp + 2048);
      f32x4 e0 = __builtin_amdgcn_mfma_f32_16x16x32_bf16(qv, kf0, (f32x4){0.f,0.f,0.f,0.f}, 0, 0, 0);
      f32x4 e1 = __builtin_amdgcn_mfma_f32_16x16x32_bf16(qv, kf1, (f32x4){0.f,0.f,0.f,0.f}, 0, 0, 0);
      ps0 += (fexp2f(e0[0]) + fexp2f(e0[1])) + (fexp2f(e0[2]) + fexp2f(e0[3]));
      ps1 += (fexp2f(e1[0]) + fexp2f(e1[1])) + (fexp2f(e1[2]) + fexp2f(e1[3]));
      qv = qn;
    }
  }
  ps0 += __shfl_xor(ps0, 16); ps0 += __shfl_xor(ps0, 32);
  ps1 += __shfl_xor(ps1, 16); ps1 += __shfl_xor(ps1, 32);
  if (lane < 16){
    ssum[nq][mh * 32 + lane]      = ps0;
    ssum[nq][mh * 32 + 16 + lane] = ps1;
  }
  __syncthreads();
  const float is0 = frcpf(ssum[0][row0] + ssum[1][row0] + ssum[2][row0] + ssum[3][row0]);
  const float is1 = frcpf(ssum[0][row1] + ssum[1][row1] + ssum[2][row1] + ssum[3][row1]);

  // ---- pass 2 ----
  f32x4 acc[2][4];
  #pragma unroll
  for (int ct = 0; ct < 2; ++ct)
    #pragma unroll
    for (int m2 = 0; m2 < 4; ++m2) acc[ct][m2] = (f32x4){0.f,0.f,0.f,0.f};

  const int pw0 = row0 * 64 + (((nq * 2 + (lg >> 1)) ^ (row0 & 7)) << 3) + (lg & 1) * 4;
  const int pw1 = row1 * 64 + (((nq * 2 + (lg >> 1)) ^ (row1 & 7)) << 3) + (lg & 1) * 4;
  int pfo[4][2];
  #pragma unroll
  for (int m2 = 0; m2 < 4; ++m2){
    const int prow = m2 * 16 + lr;
    #pragma unroll
    for (int ks = 0; ks < 2; ++ks)
      pfo[m2][ks] = prow * 64 + (((ks * 4 + lg) ^ (prow & 7)) << 3);
  }

  const unsigned short* qp = qfw + 2048;     // q tile for s+1
  const unsigned short* afp = afw + TSZ_;    // x0f tile for s+1
  float* attw0 = att + ((size_t)b * W_ + m0 + row0) * W_ + nq * 16 + lg * 4;
  float* attw1 = attw0 + (size_t)16 * W_;

  bf16x8 qv = *(const bf16x8*)qfw;           // q for s=0
  bf16x8 af0 = *(const bf16x8*)(afw);        // A-frags for s=0 (ct*2+ks order)
  bf16x8 af1 = *(const bf16x8*)(afw + 512);
  bf16x8 af2 = *(const bf16x8*)(afw + 1024);
  bf16x8 af3 = *(const bf16x8*)(afw + 1536);

  for (int s = 0; s < NT64_; ++s){
    const int cur = s & 1;

    // energy (2 quarters, shared qv) -> P[cur]
    f32x4 e0 = __builtin_amdgcn_mfma_f32_16x16x32_bf16(qv, kf0, (f32x4){0.f,0.f,0.f,0.f}, 0, 0, 0);
    f32x4 e1 = __builtin_amdgcn_mfma_f32_16x16x32_bf16(qv, kf1, (f32x4){0.f,0.f,0.f,0.f}, 0, 0, 0);
    f32x4 p0, p1;
    #pragma unroll
    for (int r = 0; r < 4; ++r){
      p0[r] = fexp2f(e0[r]) * is0;
      p1[r] = fexp2f(e1[r]) * is1;
    }
    uint2 pv0; pv0.x = cvtpk(p0[0], p0[1]); pv0.y = cvtpk(p0[2], p0[3]);
    uint2 pv1; pv1.x = cvtpk(p1[0], p1[1]); pv1.y = cvtpk(p1[2], p1[3]);
    *(uint2*)(&Plds[cur][0] + pw0) = pv0;
    *(uint2*)(&Plds[cur][0] + pw1) = pv1;

    // pure-LDS barrier: P[cur] visible; NO vmcnt drain
    asm volatile("s_waitcnt lgkmcnt(0)" ::: "memory");
    __builtin_amdgcn_sched_barrier(0);
    __builtin_amdgcn_s_barrier();

    // prefetch next-tile operands + store att(s) — NORMAL stores (via L2)
    qv = *(const bf16x8*)qp;
    qp = (s == NT64_ - 2) ? qfw : (qp + 2048);
    bf16x8 an0 = *(const bf16x8*)(afp);
    bf16x8 an1 = *(const bf16x8*)(afp + 512);
    bf16x8 an2 = *(const bf16x8*)(afp + 1024);
    bf16x8 an3 = *(const bf16x8*)(afp + 1536);
    afp = (s == NT64_ - 2) ? afw : (afp + TSZ_);
    *(f32x4*)attw0 = p0;
    *(f32x4*)attw1 = p1;
    attw0 += 64; attw1 += 64;

    // PV: A = x0 fragments (registers), B = P[cur] (swizzled LDS)
    const unsigned short* Pb = &Plds[cur][0];
    bf16x8 pf[4][2];
    __builtin_amdgcn_s_setprio(1);
    #pragma unroll
    for (int m2 = 0; m2 < 4; ++m2)
      #pragma unroll
      for (int ks = 0; ks < 2; ++ks)
        pf[m2][ks] = *(const bf16x8*)(Pb + pfo[m2][ks]);
    #pragma unroll
    for (int m2 = 0; m2 < 4; ++m2){
      acc[0][m2] = __builtin_amdgcn_mfma_f32_16x16x32_bf16(af0, pf[m2][0], acc[0][m2], 0, 0, 0);
      acc[0][m2] = __builtin_amdgcn_mfma_f32_16x16x32_bf16(af1, pf[m2][1], acc[0][m2], 0, 0, 0);
      acc[1][m2] = __builtin_amdgcn_mfma_f32_16x16x32_bf16(af2, pf[m2][0], acc[1][m2], 0, 0, 0);
      acc[1][m2] = __builtin_amdgcn_mfma_f32_16x16x32_bf16(af3, pf[m2][1], acc[1][m2], 0, 0, 0);
    }
    __builtin_amdgcn_s_setprio(0);

    af0 = an0; af1 = an1; af2 = an2; af3 = an3;
  }

  // ---- epilogue: out[c][m] = gamma*acc + x1 (normal loads/stores) ----
  const float g = gamma[0];
  const float* x1b = x1 + (size_t)b * C_ * W_;
  float* outb = out + (size_t)b * C_ * W_;
  #pragma unroll
  for (int ct = 0; ct < 2; ++ct)
    #pragma unroll
    for (int m2 = 0; m2 < 4; ++m2)
      #pragma unroll
      for (int r = 0; r < 4; ++r){
        const int c = wid * 32 + ct * 16 + lg * 4 + r;
        const size_t idx = (size_t)c * W_ + m0 + m2 * 16 + lr;
        outb[idx] = fmaf(g, acc[ct][m2][r], x1b[idx]);
      }
}

extern "C" void kernel_launch(void* const* d_in, const int* in_sizes, int n_in,
                              void* d_out, int out_size, void* d_ws, size_t ws_size,
                              hipStream_t stream)
{
  (void)in_sizes; (void)n_in; (void)out_size; (void)ws_size;
  const float* x0    = (const float*)d_in[0];
  const float* x1    = (const float*)d_in[1];
  const float* wq    = (const float*)d_in[2];
  const float* bq    = (const float*)d_in[3];
  const float* wk    = (const float*)d_in[4];
  const float* bk    = (const float*)d_in[5];
  const float* gamma = (const float*)d_in[6];

  unsigned short* qf  = (unsigned short*)d_ws;                   // 1 MB (fragment layout)
  unsigned short* kT  = qf + (size_t)B_ * W_ * DQK_;             // 1 MB
  unsigned short* x0f = kT + (size_t)B_ * W_ * DQK_;             // 8 MB fragment tiles

  float* out = (float*)d_out;                                    // [B][C][W]
  float* att = out + (size_t)B_ * C_ * W_;                       // [B][W][W]

  sa_prep <<<dim3(64, 4), 512, 0, stream>>>(x0, x1, wq, bq, wk, bk, qf, kT, x0f);
  sa_fused<<<256, 512, 0, stream>>>(qf, kT, x0f, x1, gamma, out, att);
}